// Round 6
// baseline (17.553 us; speedup 1.0000x reference)
//
#include <hip/hip_runtime.h>
#include <math.h>

// ---------------------------------------------------------------------------
// Compile-time PGA Cl(3,0,1) tables.
// Blade basis ordering (matches reference):
//   1, e0, e1, e2, e3, e01, e02, e03, e12, e13, e23, e012, e013, e023, e123, e0123
// Bitmask representation: bit0=e0, bit1=e1, bit2=e2, bit3=e3.
// ---------------------------------------------------------------------------
namespace ct {

constexpr int MASK[16] = {0, 1, 2, 4, 8, 3, 5, 9, 6, 10, 12, 7, 11, 13, 14, 15};
constexpr int IDX[16]  = {0, 1, 2, 5, 3, 6, 8, 11, 4, 7, 9, 12, 10, 13, 14, 15};
constexpr int GRADE[16] = {0, 1, 1, 1, 1, 2, 2, 2, 2, 2, 2, 3, 3, 3, 3, 4};

constexpr int popc(int v) { int c = 0; while (v) { c += v & 1; v >>= 1; } return c; }

constexpr int rs(int a, int b) {
    int s = 0;
    a >>= 1;
    while (a) { s += popc(a & b); a >>= 1; }
    return (s & 1) ? -1 : 1;
}

struct Tab { int sgn[16][16]; int idx[16][16]; };

constexpr Tab make_gp() {
    Tab t{};
    for (int i = 0; i < 16; ++i)
        for (int j = 0; j < 16; ++j) {
            int a = MASK[i], b = MASK[j];
            if (a & b & 1) { t.sgn[i][j] = 0; t.idx[i][j] = 0; }
            else           { t.sgn[i][j] = rs(a, b); t.idx[i][j] = IDX[a ^ b]; }
        }
    return t;
}

constexpr Tab make_jn() {
    Tab t{};
    for (int i = 0; i < 16; ++i)
        for (int j = 0; j < 16; ++j) {
            int a = MASK[i], b = MASK[j];
            int ca = 15 ^ a, cb = 15 ^ b;
            if (ca & cb) { t.sgn[i][j] = 0; t.idx[i][j] = 0; }
            else {
                int m = ca | cb;      // wedge in dual space
                int p = 15 ^ m;       // undual
                t.sgn[i][j] = rs(a, ca) * rs(b, cb) * rs(ca, cb) * rs(p, m);
                t.idx[i][j] = IDX[p];
            }
        }
    return t;
}

constexpr Tab GP = make_gp();
constexpr Tab JN = make_jn();

} // namespace ct

// ---------------------------------------------------------------------------
// One thread per multivector. Coalesced global loads/stores via WAVE-PRIVATE
// LDS slabs (no __syncthreads; wave_barrier pins LDS write->read order).
// Register-pressure-trimmed (in-place gating, no folded weight arrays) +
// __launch_bounds__(256,4) so all 4 grid-supplied waves/SIMD are resident.
// ---------------------------------------------------------------------------
__global__ __launch_bounds__(256, 4) void mvffn_kernel(
    const float* __restrict__ x,
    const float* __restrict__ w1,  const float* __restrict__ v1,  const float* __restrict__ b1,
    const float* __restrict__ w2g, const float* __restrict__ v2g, const float* __restrict__ b2g,
    const float* __restrict__ w2j, const float* __restrict__ v2j, const float* __restrict__ b2j,
    float* __restrict__ out, int n)
{
    const int tid  = threadIdx.x;
    const int lane = tid & 63;
    const int wv   = tid >> 6;                    // wave id within block (0..3)
    const int mv0  = blockIdx.x * 256;            // first MV of this block
    const int mv   = mv0 + tid;
    const bool full = (mv0 + 256 <= n);

    __shared__ float4 sh[4][64 * 5];              // 4 wave-private 5 KB slabs

    // ---- load: coalesced global -> LDS -> per-thread registers ----
    float X[16];
    if (full) {
        const float4* gx = reinterpret_cast<const float4*>(x)
                         + (size_t)(mv0 + wv * 64) * 4;     // wave's 4 KB slab
        #pragma unroll
        for (int k = 0; k < 4; ++k) {
            const int u = lane + 64 * k;                    // coalesced, 16 lines/inst
            sh[wv][(u >> 2) * 5 + (u & 3)] = gx[u];
        }
        __builtin_amdgcn_wave_barrier();                    // keep write->read order
        #pragma unroll
        for (int j = 0; j < 4; ++j) {
            float4 q = sh[wv][lane * 5 + j];
            X[4 * j + 0] = q.x; X[4 * j + 1] = q.y; X[4 * j + 2] = q.z; X[4 * j + 3] = q.w;
        }
        __builtin_amdgcn_wave_barrier();                    // reads before slab reuse
    } else if (mv < n) {                                    // tail block (rare)
        const float4* xv = reinterpret_cast<const float4*>(x) + (size_t)mv * 4;
        #pragma unroll
        for (int j = 0; j < 4; ++j) {
            float4 q = xv[j];
            X[4 * j + 0] = q.x; X[4 * j + 1] = q.y; X[4 * j + 2] = q.z; X[4 * j + 3] = q.w;
        }
    }

    float o[16];
    if (full || mv < n) {
        // ---- uniform parameters (wave-uniform -> SGPRs) ----
        float W1[5], W2G[5], W2J[5], V1[4], V2G[4], V2J[4];
        #pragma unroll
        for (int i = 0; i < 5; ++i) { W1[i] = w1[i]; W2G[i] = w2g[i]; W2J[i] = w2j[i]; }
        #pragma unroll
        for (int i = 0; i < 4; ++i) { V1[i] = v1[i]; V2G[i] = v2g[i]; V2J[i] = v2j[i]; }
        const float B1 = b1[0], B2G = b2g[0], B2J = b2j[0];

        // ---- MVLinear #1: per-grade scale + e0*x branch + scalar bias ----
        float xp[16];
        #pragma unroll
        for (int k = 0; k < 16; ++k) xp[k] = X[k] * W1[ct::GRADE[k]];
        xp[0]  += B1;
        xp[1]  += V1[1] * X[0];                     // e0   <- 1
        xp[5]  += V1[2] * X[2];                     // e01  <- e1
        xp[6]  += V1[2] * X[3];                     // e02  <- e2
        xp[7]  += V1[2] * X[4];                     // e03  <- e3
        xp[11] += V1[3] * X[8];                     // e012 <- e12
        xp[12] += V1[3] * X[9];                     // e013 <- e13
        xp[13] += V1[3] * X[10];                    // e023 <- e23

        // ---- gated GELU (exact), applied IN PLACE: xp becomes x_gated ----
        const float s0 = xp[0];
        const float gate = 0.5f * s0 * (1.0f + erff(s0 * 0.70710678118654752f));
        #pragma unroll
        for (int k = 0; k < 16; ++k) xp[k] *= gate;

        // ---- bilinear forms: geometric product (192) + join (81) ----
        float gp[16], jn[16];
        #pragma unroll
        for (int k = 0; k < 16; ++k) { gp[k] = 0.0f; jn[k] = 0.0f; }

        #pragma unroll
        for (int i = 0; i < 16; ++i) {
            #pragma unroll
            for (int j = 0; j < 16; ++j) {
                if (ct::GP.sgn[i][j] > 0)      gp[ct::GP.idx[i][j]] += X[i] * xp[j];
                else if (ct::GP.sgn[i][j] < 0) gp[ct::GP.idx[i][j]] -= X[i] * xp[j];
                if (ct::JN.sgn[i][j] > 0)      jn[ct::JN.idx[i][j]] += X[i] * xp[j];
                else if (ct::JN.sgn[i][j] < 0) jn[ct::JN.idx[i][j]] -= X[i] * xp[j];
            }
        }

        // ---- join gated by reference pseudoscalar, applied once ----
        const float ps = X[15];
        #pragma unroll
        for (int k = 0; k < 16; ++k) jn[k] *= ps;

        // ---- second linears summed ----
        #pragma unroll
        for (int k = 0; k < 16; ++k)
            o[k] = gp[k] * W2G[ct::GRADE[k]] + jn[k] * W2J[ct::GRADE[k]];
        o[0]  += B2G + B2J;
        o[1]  += V2G[1] * gp[0]  + V2J[1] * jn[0];
        o[5]  += V2G[2] * gp[2]  + V2J[2] * jn[2];
        o[6]  += V2G[2] * gp[3]  + V2J[2] * jn[3];
        o[7]  += V2G[2] * gp[4]  + V2J[2] * jn[4];
        o[11] += V2G[3] * gp[8]  + V2J[3] * jn[8];
        o[12] += V2G[3] * gp[9]  + V2J[3] * jn[9];
        o[13] += V2G[3] * gp[10] + V2J[3] * jn[10];
    }

    // ---- store: registers -> LDS -> coalesced global ----
    if (full) {
        #pragma unroll
        for (int j = 0; j < 4; ++j)
            sh[wv][lane * 5 + j] =
                make_float4(o[4 * j + 0], o[4 * j + 1], o[4 * j + 2], o[4 * j + 3]);
        __builtin_amdgcn_wave_barrier();
        float4* gy = reinterpret_cast<float4*>(out) + (size_t)(mv0 + wv * 64) * 4;
        #pragma unroll
        for (int k = 0; k < 4; ++k) {
            const int u = lane + 64 * k;                    // coalesced store
            gy[u] = sh[wv][(u >> 2) * 5 + (u & 3)];
        }
    } else if (mv < n) {
        float4* ov = reinterpret_cast<float4*>(out) + (size_t)mv * 4;
        #pragma unroll
        for (int j = 0; j < 4; ++j)
            ov[j] = make_float4(o[4 * j + 0], o[4 * j + 1], o[4 * j + 2], o[4 * j + 3]);
    }
}

extern "C" void kernel_launch(void* const* d_in, const int* in_sizes, int n_in,
                              void* d_out, int out_size, void* d_ws, size_t ws_size,
                              hipStream_t stream) {
    const float* x   = (const float*)d_in[0];
    const float* w1  = (const float*)d_in[1];
    const float* v1  = (const float*)d_in[2];
    const float* b1  = (const float*)d_in[3];
    const float* w2g = (const float*)d_in[4];
    const float* v2g = (const float*)d_in[5];
    const float* b2g = (const float*)d_in[6];
    const float* w2j = (const float*)d_in[7];
    const float* v2j = (const float*)d_in[8];
    const float* b2j = (const float*)d_in[9];
    float* out = (float*)d_out;

    const int n = in_sizes[0] / 16;          // number of multivectors
    const int block = 256;
    const int grid = (n + block - 1) / block;
    mvffn_kernel<<<grid, block, 0, stream>>>(x, w1, v1, b1, w2g, v2g, b2g,
                                             w2j, v2j, b2j, out, n);
}

// Round 7
// 13.002 us; speedup vs baseline: 1.3500x; 1.3500x over previous
//
#include <hip/hip_runtime.h>
#include <math.h>

// ---------------------------------------------------------------------------
// Compile-time PGA Cl(3,0,1) tables.
// Blade basis ordering (matches reference):
//   1, e0, e1, e2, e3, e01, e02, e03, e12, e13, e23, e012, e013, e023, e123, e0123
// Bitmask representation: bit0=e0, bit1=e1, bit2=e2, bit3=e3.
// ---------------------------------------------------------------------------
namespace ct {

constexpr int MASK[16] = {0, 1, 2, 4, 8, 3, 5, 9, 6, 10, 12, 7, 11, 13, 14, 15};
constexpr int IDX[16]  = {0, 1, 2, 5, 3, 6, 8, 11, 4, 7, 9, 12, 10, 13, 14, 15};
constexpr int GRADE[16] = {0, 1, 1, 1, 1, 2, 2, 2, 2, 2, 2, 3, 3, 3, 3, 4};

constexpr int popc(int v) { int c = 0; while (v) { c += v & 1; v >>= 1; } return c; }

constexpr int rs(int a, int b) {
    int s = 0;
    a >>= 1;
    while (a) { s += popc(a & b); a >>= 1; }
    return (s & 1) ? -1 : 1;
}

struct Tab { int sgn[16][16]; int idx[16][16]; };

constexpr Tab make_gp() {
    Tab t{};
    for (int i = 0; i < 16; ++i)
        for (int j = 0; j < 16; ++j) {
            int a = MASK[i], b = MASK[j];
            if (a & b & 1) { t.sgn[i][j] = 0; t.idx[i][j] = 0; }
            else           { t.sgn[i][j] = rs(a, b); t.idx[i][j] = IDX[a ^ b]; }
        }
    return t;
}

constexpr Tab make_jn() {
    Tab t{};
    for (int i = 0; i < 16; ++i)
        for (int j = 0; j < 16; ++j) {
            int a = MASK[i], b = MASK[j];
            int ca = 15 ^ a, cb = 15 ^ b;
            if (ca & cb) { t.sgn[i][j] = 0; t.idx[i][j] = 0; }
            else {
                int m = ca | cb;      // wedge in dual space
                int p = 15 ^ m;       // undual
                t.sgn[i][j] = rs(a, ca) * rs(b, cb) * rs(ca, cb) * rs(p, m);
                t.idx[i][j] = IDX[p];
            }
        }
    return t;
}

constexpr Tab GP = make_gp();
constexpr Tab JN = make_jn();

} // namespace ct

// ---------------------------------------------------------------------------
// One thread per multivector. Coalesced global I/O via WAVE-PRIVATE LDS slabs
// (no __syncthreads). Bilinear forms in GATHER form: per output component k,
// sum its GP/JN terms into two scalars and fold the second linears in
// immediately -> peak live set ~X[16]+xp[16]+o[] instead of +gp[16]+jn[16],
// targeting <=128 VGPR so the grid's 4 waves/SIMD are all resident.
// ---------------------------------------------------------------------------
__global__ __launch_bounds__(256) void mvffn_kernel(
    const float* __restrict__ x,
    const float* __restrict__ w1,  const float* __restrict__ v1,  const float* __restrict__ b1,
    const float* __restrict__ w2g, const float* __restrict__ v2g, const float* __restrict__ b2g,
    const float* __restrict__ w2j, const float* __restrict__ v2j, const float* __restrict__ b2j,
    float* __restrict__ out, int n)
{
    const int tid  = threadIdx.x;
    const int lane = tid & 63;
    const int wv   = tid >> 6;                    // wave id within block (0..3)
    const int mv0  = blockIdx.x * 256;            // first MV of this block
    const int mv   = mv0 + tid;
    const bool full = (mv0 + 256 <= n);

    __shared__ float4 sh[4][64 * 5];              // 4 wave-private 5 KB slabs

    // ---- load: coalesced global -> LDS -> per-thread registers ----
    float X[16];
    if (full) {
        const float4* gx = reinterpret_cast<const float4*>(x)
                         + (size_t)(mv0 + wv * 64) * 4;     // wave's 4 KB slab
        #pragma unroll
        for (int k = 0; k < 4; ++k) {
            const int u = lane + 64 * k;                    // coalesced, 16 lines/inst
            sh[wv][(u >> 2) * 5 + (u & 3)] = gx[u];
        }
        __builtin_amdgcn_wave_barrier();                    // keep write->read order
        #pragma unroll
        for (int j = 0; j < 4; ++j) {
            float4 q = sh[wv][lane * 5 + j];
            X[4 * j + 0] = q.x; X[4 * j + 1] = q.y; X[4 * j + 2] = q.z; X[4 * j + 3] = q.w;
        }
        __builtin_amdgcn_wave_barrier();                    // reads before slab reuse
    } else if (mv < n) {                                    // tail block (rare)
        const float4* xv = reinterpret_cast<const float4*>(x) + (size_t)mv * 4;
        #pragma unroll
        for (int j = 0; j < 4; ++j) {
            float4 q = xv[j];
            X[4 * j + 0] = q.x; X[4 * j + 1] = q.y; X[4 * j + 2] = q.z; X[4 * j + 3] = q.w;
        }
    }

    float o[16];
    if (full || mv < n) {
        // ---- uniform parameters ----
        float W1[5], W2G[5], W2J[5], V1[4], V2G[4], V2J[4];
        #pragma unroll
        for (int i = 0; i < 5; ++i) { W1[i] = w1[i]; W2G[i] = w2g[i]; W2J[i] = w2j[i]; }
        #pragma unroll
        for (int i = 0; i < 4; ++i) { V1[i] = v1[i]; V2G[i] = v2g[i]; V2J[i] = v2j[i]; }
        const float B1 = b1[0], B2G = b2g[0], B2J = b2j[0];

        // ---- MVLinear #1: per-grade scale + e0*x branch + scalar bias ----
        float xp[16];
        #pragma unroll
        for (int k = 0; k < 16; ++k) xp[k] = X[k] * W1[ct::GRADE[k]];
        xp[0]  += B1;
        xp[1]  += V1[1] * X[0];                     // e0   <- 1
        xp[5]  += V1[2] * X[2];                     // e01  <- e1
        xp[6]  += V1[2] * X[3];                     // e02  <- e2
        xp[7]  += V1[2] * X[4];                     // e03  <- e3
        xp[11] += V1[3] * X[8];                     // e012 <- e12
        xp[12] += V1[3] * X[9];                     // e013 <- e13
        xp[13] += V1[3] * X[10];                    // e023 <- e23

        // ---- gated GELU (exact), in place: xp becomes x_gated ----
        const float s0 = xp[0];
        const float gate = 0.5f * s0 * (1.0f + erff(s0 * 0.70710678118654752f));
        #pragma unroll
        for (int k = 0; k < 16; ++k) xp[k] *= gate;

        const float ps = X[15];

        // ---- bilinear forms in GATHER form + fused second linears ----
        // Short-lived stashes for the e0-branch cross terms (source k < dest k).
        float c1 = 0.f, c5 = 0.f, c6 = 0.f, c7 = 0.f, c11 = 0.f, c12 = 0.f, c13 = 0.f;

        #pragma unroll
        for (int k = 0; k < 16; ++k) {
            float g = 0.f, h = 0.f;
            #pragma unroll
            for (int i = 0; i < 16; ++i) {
                #pragma unroll
                for (int j = 0; j < 16; ++j) {
                    if (ct::GP.sgn[i][j] > 0 && ct::GP.idx[i][j] == k)      g += X[i] * xp[j];
                    else if (ct::GP.sgn[i][j] < 0 && ct::GP.idx[i][j] == k) g -= X[i] * xp[j];
                    if (ct::JN.sgn[i][j] > 0 && ct::JN.idx[i][j] == k)      h += X[i] * xp[j];
                    else if (ct::JN.sgn[i][j] < 0 && ct::JN.idx[i][j] == k) h -= X[i] * xp[j];
                }
            }
            h *= ps;                                 // join gated by reference ps

            float val = g * W2G[ct::GRADE[k]] + h * W2J[ct::GRADE[k]];
            // e0-branch cross contributions (dest index > k, stash now)
            if (k == 0)  { val += B2G + B2J; c1  = V2G[1] * g + V2J[1] * h; }
            if (k == 2)  { c5  = V2G[2] * g + V2J[2] * h; }
            if (k == 3)  { c6  = V2G[2] * g + V2J[2] * h; }
            if (k == 4)  { c7  = V2G[2] * g + V2J[2] * h; }
            if (k == 8)  { c11 = V2G[3] * g + V2J[3] * h; }
            if (k == 9)  { c12 = V2G[3] * g + V2J[3] * h; }
            if (k == 10) { c13 = V2G[3] * g + V2J[3] * h; }
            // fold stashed cross terms into their destination
            if (k == 1)  val += c1;
            if (k == 5)  val += c5;
            if (k == 6)  val += c6;
            if (k == 7)  val += c7;
            if (k == 11) val += c11;
            if (k == 12) val += c12;
            if (k == 13) val += c13;
            o[k] = val;
        }
    }

    // ---- store: registers -> LDS -> coalesced global ----
    if (full) {
        #pragma unroll
        for (int j = 0; j < 4; ++j)
            sh[wv][lane * 5 + j] =
                make_float4(o[4 * j + 0], o[4 * j + 1], o[4 * j + 2], o[4 * j + 3]);
        __builtin_amdgcn_wave_barrier();
        float4* gy = reinterpret_cast<float4*>(out) + (size_t)(mv0 + wv * 64) * 4;
        #pragma unroll
        for (int k = 0; k < 4; ++k) {
            const int u = lane + 64 * k;                    // coalesced store
            gy[u] = sh[wv][(u >> 2) * 5 + (u & 3)];
        }
    } else if (mv < n) {
        float4* ov = reinterpret_cast<float4*>(out) + (size_t)mv * 4;
        #pragma unroll
        for (int j = 0; j < 4; ++j)
            ov[j] = make_float4(o[4 * j + 0], o[4 * j + 1], o[4 * j + 2], o[4 * j + 3]);
    }
}

extern "C" void kernel_launch(void* const* d_in, const int* in_sizes, int n_in,
                              void* d_out, int out_size, void* d_ws, size_t ws_size,
                              hipStream_t stream) {
    const float* x   = (const float*)d_in[0];
    const float* w1  = (const float*)d_in[1];
    const float* v1  = (const float*)d_in[2];
    const float* b1  = (const float*)d_in[3];
    const float* w2g = (const float*)d_in[4];
    const float* v2g = (const float*)d_in[5];
    const float* b2g = (const float*)d_in[6];
    const float* w2j = (const float*)d_in[7];
    const float* v2j = (const float*)d_in[8];
    const float* b2j = (const float*)d_in[9];
    float* out = (float*)d_out;

    const int n = in_sizes[0] / 16;          // number of multivectors
    const int block = 256;
    const int grid = (n + block - 1) / block;
    mvffn_kernel<<<grid, block, 0, stream>>>(x, w1, v1, b1, w2g, v2g, b2g,
                                             w2j, v2j, b2j, out, n);
}